// Round 1
// baseline (329.984 us; speedup 1.0000x reference)
//
#include <hip/hip_runtime.h>
#include <math.h>

#define NROWS 2048
#define DIMS  512
#define KG    5
#define BM    64
#define BK    16

// invc[k] = 1/(2*gamma^2), gammas = {2,1,0.5,0.25,0.125}
__device__ __constant__ float c_invc[KG] = {0.125f, 0.5f, 2.0f, 8.0f, 32.0f};

// ---------------- row norms ----------------
__global__ void rownorm_kernel(const float* __restrict__ Xs, const float* __restrict__ Xt,
                               float* __restrict__ ns, float* __restrict__ nt) {
    const int row = blockIdx.x;
    const float* X = blockIdx.y ? Xt : Xs;
    float* out = blockIdx.y ? nt : ns;
    const float* r = X + (size_t)row * DIMS;
    float s = 0.f;
    for (int j = threadIdx.x; j < DIMS; j += 256) { float v = r[j]; s += v * v; }
    __shared__ float red[256];
    red[threadIdx.x] = s;
    __syncthreads();
    for (int off = 128; off > 0; off >>= 1) {
        if (threadIdx.x < off) red[threadIdx.x] += red[threadIdx.x + off];
        __syncthreads();
    }
    if (threadIdx.x == 0) out[row] = red[0];
}

// ---------------- fused gram + exp + reduce ----------------
// pair z: 0 = XX (Xs,Xs), 1 = YY (Xt,Xt), 2 = XY (Xs rows, Xt cols)
__global__ __launch_bounds__(256) void gram_kernel(const float* __restrict__ Xs,
                                                   const float* __restrict__ Xt,
                                                   const float* __restrict__ ns,
                                                   const float* __restrict__ nt,
                                                   double* __restrict__ sums) {
    const int pair = blockIdx.z;
    const float* A  = (pair == 1) ? Xt : Xs;
    const float* B  = (pair == 0) ? Xs : Xt;
    const float* na = (pair == 1) ? nt : ns;
    const float* nb = (pair == 0) ? ns : nt;

    __shared__ float As[BK][BM + 4];
    __shared__ float Bs[BK][BM + 4];
    __shared__ float red[KG][4];

    const int tx = threadIdx.x;      // 0..15
    const int ty = threadIdx.y;      // 0..15
    const int tid = ty * 16 + tx;
    const int row0 = blockIdx.y * BM;
    const int col0 = blockIdx.x * BM;

    const int lk = tid & 15;         // k within tile
    const int lm = tid >> 4;         // base row within tile

    float acc[4][4] = {};

    for (int kt = 0; kt < DIMS; kt += BK) {
#pragma unroll
        for (int p = 0; p < 4; ++p) {
            const int m = lm + p * 16;
            As[lk][m] = A[(size_t)(row0 + m) * DIMS + kt + lk];
            Bs[lk][m] = B[(size_t)(col0 + m) * DIMS + kt + lk];
        }
        __syncthreads();
#pragma unroll
        for (int k = 0; k < BK; ++k) {
            const float4 a = *(const float4*)&As[k][ty * 4];
            const float4 b = *(const float4*)&Bs[k][tx * 4];
            acc[0][0] += a.x * b.x; acc[0][1] += a.x * b.y; acc[0][2] += a.x * b.z; acc[0][3] += a.x * b.w;
            acc[1][0] += a.y * b.x; acc[1][1] += a.y * b.y; acc[1][2] += a.y * b.z; acc[1][3] += a.y * b.w;
            acc[2][0] += a.z * b.x; acc[2][1] += a.z * b.y; acc[2][2] += a.z * b.z; acc[2][3] += a.z * b.w;
            acc[3][0] += a.w * b.x; acc[3][1] += a.w * b.y; acc[3][2] += a.w * b.z; acc[3][3] += a.w * b.w;
        }
        __syncthreads();
    }

    // epilogue: d = |a|^2 + |b|^2 - 2 a.b ; accumulate exp(-d*invc[g])
    float lsum[KG] = {0.f, 0.f, 0.f, 0.f, 0.f};
#pragma unroll
    for (int i = 0; i < 4; ++i) {
        const float nai = na[row0 + ty * 4 + i];
#pragma unroll
        for (int j = 0; j < 4; ++j) {
            const float d = nai + nb[col0 + tx * 4 + j] - 2.f * acc[i][j];
#pragma unroll
            for (int g = 0; g < KG; ++g) lsum[g] += __expf(-d * c_invc[g]);
        }
    }

    // reduce 5 partial sums across the block (wave shuffle, then LDS)
    const int lane = tid & 63;
    const int wv = tid >> 6;
#pragma unroll
    for (int g = 0; g < KG; ++g) {
        float v = lsum[g];
        for (int off = 32; off > 0; off >>= 1) v += __shfl_down(v, off, 64);
        if (lane == 0) red[g][wv] = v;
    }
    __syncthreads();
    if (tid < KG) {
        const double s = (double)red[tid][0] + (double)red[tid][1] +
                         (double)red[tid][2] + (double)red[tid][3];
        atomicAdd(&sums[pair * KG + tid], s);
    }
}

// ---------------- h pairs: h[g][j] = g[g, 2j, 2j+1] ----------------
__global__ void hpairs_kernel(const float* __restrict__ Xs, const float* __restrict__ Xt,
                              const float* __restrict__ ns, const float* __restrict__ nt,
                              float* __restrict__ h) {
    const int gtid = blockIdx.x * blockDim.x + threadIdx.x;
    const int wid = gtid >> 6;          // pair index j (1024 total)
    const int lane = threadIdx.x & 63;
    if (wid >= 1024) return;
    const int i = 2 * wid, j = 2 * wid + 1;
    const float* xsi = Xs + (size_t)i * DIMS;
    const float* xsj = Xs + (size_t)j * DIMS;
    const float* xti = Xt + (size_t)i * DIMS;
    const float* xtj = Xt + (size_t)j * DIMS;
    float dss = 0.f, dtt = 0.f, dst = 0.f, dts = 0.f;
    for (int c = lane; c < DIMS; c += 64) {
        const float a = xsi[c], b = xsj[c], p = xti[c], q = xtj[c];
        dss += a * b; dtt += p * q; dst += a * q; dts += p * b;
    }
    for (int off = 32; off > 0; off >>= 1) {
        dss += __shfl_down(dss, off, 64);
        dtt += __shfl_down(dtt, off, 64);
        dst += __shfl_down(dst, off, 64);
        dts += __shfl_down(dts, off, 64);
    }
    if (lane == 0) {
        const float nsi = ns[i], nsj = ns[j], nti = nt[i], ntj = nt[j];
#pragma unroll
        for (int g = 0; g < KG; ++g) {
            const float ic = c_invc[g];
            const float v = __expf(-(nsi + nsj - 2.f * dss) * ic)
                          + __expf(-(nti + ntj - 2.f * dtt) * ic)
                          - __expf(-(nsi + ntj - 2.f * dst) * ic)
                          - __expf(-(nti + nsj - 2.f * dts) * ic);
            h[g * 1024 + wid] = v;
        }
    }
}

// ---------------- finalize: eta, Q, QP over 31 masks, output ----------------
__global__ void finalize_kernel(const double* __restrict__ sums,
                                const float* __restrict__ h,
                                float* __restrict__ out) {
    __shared__ float h4[KG][512];
    __shared__ float hsum[KG];
    __shared__ float qdot[15];
    __shared__ float red[256];
    const int t = threadIdx.x;

    for (int k = 0; k < KG; ++k)
        for (int j2 = t; j2 < 512; j2 += 256)
            h4[k][j2] = h[k * 1024 + 2 * j2] - h[k * 1024 + 2 * j2 + 1];

    for (int k = 0; k < KG; ++k) {
        float s = 0.f;
        for (int j = t; j < 1024; j += 256) s += h[k * 1024 + j];
        red[t] = s;
        __syncthreads();
        for (int off = 128; off > 0; off >>= 1) {
            if (t < off) red[t] += red[t + off];
            __syncthreads();
        }
        if (t == 0) hsum[k] = red[0];
        __syncthreads();
    }

    // 15 upper-triangular dot products of h4 rows, one wave each (4 waves round-robin)
    const int wv = t >> 6, ln = t & 63;
    const int pa[15] = {0,0,0,0,0,1,1,1,1,2,2,2,3,3,4};
    const int pb[15] = {0,1,2,3,4,1,2,3,4,2,3,4,3,4,4};
    for (int pi = wv; pi < 15; pi += 4) {
        float s = 0.f;
        for (int j = ln; j < 512; j += 64) s += h4[pa[pi]][j] * h4[pb[pi]][j];
        for (int off = 32; off > 0; off >>= 1) s += __shfl_down(s, off, 64);
        if (ln == 0) qdot[pi] = s;
    }
    __syncthreads();

    if (t == 0) {
        const double n = 2048.0;
        double Q[KG][KG], p[KG], eta[KG];
        // unpack qdot into full symmetric matrix
        {
            int idx = 0;
            double dd[KG][KG];
            for (int a = 0; a < KG; ++a)
                for (int b = a; b < KG; ++b) { dd[a][b] = qdot[idx]; dd[b][a] = qdot[idx]; ++idx; }
            for (int a = 0; a < KG; ++a)
                for (int b = 0; b < KG; ++b) {
                    double qp = (4.0 / n) * (dd[a][b] + ((a == b) ? dd[a][a] : 0.0));
                    Q[a][b] = 2.0 * qp + ((a == b) ? 1e-5 : 0.0);
                }
        }
        for (int k = 0; k < KG; ++k) {
            p[k] = -2.0 * (double)hsum[k] / n;
            eta[k] = (sums[k] + sums[KG + k] - 2.0 * sums[2 * KG + k]) / (n * n);
        }

        double bestObj = INFINITY;
        double bestBeta[KG] = {0, 0, 0, 0, 0};
        bool haveAny = false;
        double firstBeta[KG];

        for (int mask = 1; mask < 32; ++mask) {
            double m[KG];
            for (int k = 0; k < KG; ++k) m[k] = (mask >> k) & 1 ? 1.0 : 0.0;
            double M[6][7];
            for (int a = 0; a < 6; ++a)
                for (int b = 0; b < 7; ++b) M[a][b] = 0.0;
            for (int a = 0; a < KG; ++a) {
                for (int b = 0; b < KG; ++b) M[a][b] = m[a] * Q[a][b] * m[b];
                M[a][a] += 1.0 - m[a];
                M[a][KG] = m[a];
                M[KG][a] = m[a];
                M[a][6] = -m[a] * p[a];
            }
            M[KG][6] = 1.0;
            // gaussian elimination with partial pivoting
            for (int col = 0; col < 6; ++col) {
                int piv = col;
                double mx = fabs(M[col][col]);
                for (int r = col + 1; r < 6; ++r) {
                    const double v = fabs(M[r][col]);
                    if (v > mx) { mx = v; piv = r; }
                }
                if (piv != col)
                    for (int c = col; c < 7; ++c) { const double tmp = M[col][c]; M[col][c] = M[piv][c]; M[piv][c] = tmp; }
                const double d = M[col][col];
                for (int r = col + 1; r < 6; ++r) {
                    const double f = M[r][col] / d;
                    for (int c = col; c < 7; ++c) M[r][c] -= f * M[col][c];
                }
            }
            double sol[6];
            for (int r = 5; r >= 0; --r) {
                double s = M[r][6];
                for (int c = r + 1; c < 6; ++c) s -= M[r][c] * sol[c];
                sol[r] = s / M[r][r];
            }
            double beta[KG];
            for (int k = 0; k < KG; ++k) beta[k] = sol[k] * m[k];
            if (mask == 1) for (int k = 0; k < KG; ++k) firstBeta[k] = beta[k];
            double obj = 0.0;
            for (int a = 0; a < KG; ++a) {
                double qb = 0.0;
                for (int b = 0; b < KG; ++b) qb += Q[a][b] * beta[b];
                obj += 0.5 * beta[a] * qb + p[a] * beta[a];
            }
            bool feas = true;
            for (int k = 0; k < KG; ++k) if (!(beta[k] >= -1e-7)) feas = false;
            if (feas && obj < bestObj) {
                bestObj = obj;
                for (int k = 0; k < KG; ++k) bestBeta[k] = beta[k];
                haveAny = true;
            }
        }
        if (!haveAny) for (int k = 0; k < KG; ++k) bestBeta[k] = firstBeta[k];

        double o = 0.0;
        for (int k = 0; k < KG; ++k) o += eta[k] * bestBeta[k];
        out[0] = (float)o;
    }
}

// ---------------- launch ----------------
extern "C" void kernel_launch(void* const* d_in, const int* in_sizes, int n_in,
                              void* d_out, int out_size, void* d_ws, size_t ws_size,
                              hipStream_t stream) {
    const float* Xs = (const float*)d_in[0];
    const float* Xt = (const float*)d_in[1];
    float* out = (float*)d_out;

    char* ws = (char*)d_ws;
    double* sums = (double*)ws;                    // 15 doubles (120 B), reserve 128
    float* ns = (float*)(ws + 128);                // 2048 f32
    float* nt = (float*)(ws + 128 + 8192);         // 2048 f32
    float* h  = (float*)(ws + 128 + 16384);        // 5*1024 f32
    // total ws use: ~37 KB

    hipMemsetAsync(d_ws, 0, 128, stream);          // zero the sum accumulators each call
    rownorm_kernel<<<dim3(NROWS, 2), 256, 0, stream>>>(Xs, Xt, ns, nt);
    gram_kernel<<<dim3(32, 32, 3), dim3(16, 16), 0, stream>>>(Xs, Xt, ns, nt, sums);
    hpairs_kernel<<<dim3(256), dim3(256), 0, stream>>>(Xs, Xt, ns, nt, h);
    finalize_kernel<<<1, 256, 0, stream>>>(sums, h, out);
}

// Round 2
// 65.420 us; speedup vs baseline: 5.0441x; 5.0441x over previous
//
#include <hip/hip_runtime.h>
#include <math.h>

#define NROWS 2048
#define DIMS  512
#define KG    5
#define BM    128
#define BK    32

// invc[k] = 1/(2*gamma^2), gammas = {2,1,0.5,0.25,0.125}
__device__ __constant__ float c_invc[KG] = {0.125f, 0.5f, 2.0f, 8.0f, 32.0f};

typedef __attribute__((ext_vector_type(8))) short bf16x8;
typedef __attribute__((ext_vector_type(4))) float f32x4;

__device__ __forceinline__ unsigned short f2bf(float x) {
    unsigned int u = __float_as_uint(x);
    unsigned int r = (u + 0x7fffu + ((u >> 16) & 1u)) >> 16;
    return (unsigned short)r;
}

// ---------------- row norms ----------------
__global__ void rownorm_kernel(const float* __restrict__ Xs, const float* __restrict__ Xt,
                               float* __restrict__ ns, float* __restrict__ nt) {
    const int row = blockIdx.x;
    const float* X = blockIdx.y ? Xt : Xs;
    float* out = blockIdx.y ? nt : ns;
    const float* r = X + (size_t)row * DIMS;
    float s = 0.f;
    for (int j = threadIdx.x; j < DIMS; j += 256) { float v = r[j]; s += v * v; }
    __shared__ float red[256];
    red[threadIdx.x] = s;
    __syncthreads();
    for (int off = 128; off > 0; off >>= 1) {
        if (threadIdx.x < off) red[threadIdx.x] += red[threadIdx.x + off];
        __syncthreads();
    }
    if (threadIdx.x == 0) out[row] = red[0];
}

// ---------------- MFMA gram + exp + reduce ----------------
// pair z: 0 = XX (upper tri, x2, diag analytic), 1 = YY (same), 2 = XY (full)
__global__ __launch_bounds__(256) void gram_mfma_kernel(const float* __restrict__ Xs,
                                                        const float* __restrict__ Xt,
                                                        const float* __restrict__ ns,
                                                        const float* __restrict__ nt,
                                                        double* __restrict__ sums) {
    const int pair = blockIdx.z;
    const int bx = blockIdx.x, by = blockIdx.y;
    if (pair < 2 && bx < by) return;   // triangular grid for symmetric pairs

    const float* A  = (pair == 1) ? Xt : Xs;
    const float* B  = (pair == 0) ? Xs : Xt;
    const float* na = (pair == 1) ? nt : ns;
    const float* nb = (pair == 0) ? ns : nt;
    const int row0 = by * BM, col0 = bx * BM;

    // swizzled bf16 tiles: row r occupies 64B; k-octet o stored at slot (o ^ ((r>>1)&3))
    __shared__ unsigned short Asm[BM * BK];   // 8 KB
    __shared__ unsigned short Bsm[BM * BK];   // 8 KB
    __shared__ float redf[KG][4];

    const int tid = threadIdx.x;
    const int lane = tid & 63;
    const int w = tid >> 6;
    const int wr = w >> 1, wc = w & 1;        // 2x2 wave grid, 64x64 each

    f32x4 acc[4][4] = {};

    // staging geometry: pass q covers rows q*32..q*32+31; thread -> (srow, sc4)
    const int srow = tid >> 3;                // 0..31
    const int sc4  = tid & 7;                 // float4 index within 32 floats
    const int shalf = sc4 & 1;

    for (int kt = 0; kt < DIMS; kt += BK) {
#pragma unroll
        for (int q = 0; q < 4; ++q) {
            const int r = q * 32 + srow;
            const float4 av = *(const float4*)&A[(size_t)(row0 + r) * DIMS + kt + sc4 * 4];
            const float4 bv = *(const float4*)&B[(size_t)(col0 + r) * DIMS + kt + sc4 * 4];
            const int slot = (sc4 >> 1) ^ ((r >> 1) & 3);
            const int boff = r * 64 + slot * 16 + shalf * 8;
            ushort4 ab, bb;
            ab.x = f2bf(av.x); ab.y = f2bf(av.y); ab.z = f2bf(av.z); ab.w = f2bf(av.w);
            bb.x = f2bf(bv.x); bb.y = f2bf(bv.y); bb.z = f2bf(bv.z); bb.w = f2bf(bv.w);
            *(ushort4*)((char*)Asm + boff) = ab;
            *(ushort4*)((char*)Bsm + boff) = bb;
        }
        __syncthreads();

        bf16x8 af[4], bfv[4];
#pragma unroll
        for (int m = 0; m < 4; ++m) {
            const int ra = wr * 64 + m * 16 + (lane & 15);
            const int sa = (lane >> 4) ^ ((ra >> 1) & 3);
            af[m] = *(const bf16x8*)((char*)Asm + ra * 64 + sa * 16);
            const int rb = wc * 64 + m * 16 + (lane & 15);
            const int sb = (lane >> 4) ^ ((rb >> 1) & 3);
            bfv[m] = *(const bf16x8*)((char*)Bsm + rb * 64 + sb * 16);
        }
#pragma unroll
        for (int m = 0; m < 4; ++m)
#pragma unroll
            for (int n = 0; n < 4; ++n)
                acc[m][n] = __builtin_amdgcn_mfma_f32_16x16x32_bf16(af[m], bfv[n], acc[m][n], 0, 0, 0);
        __syncthreads();
    }

    // epilogue: C/D layout: col = lane&15, row = (lane>>4)*4 + reg
    float lsum[KG] = {0.f, 0.f, 0.f, 0.f, 0.f};
    const int gcol0 = col0 + wc * 64 + (lane & 15);
    const int grow0 = row0 + wr * 64 + (lane >> 4) * 4;
    const bool diagTile = (pair < 2) && (bx == by);

    float colnorm[4];
#pragma unroll
    for (int n = 0; n < 4; ++n) colnorm[n] = nb[gcol0 + n * 16];

#pragma unroll
    for (int m = 0; m < 4; ++m) {
        const float4 rn4 = *(const float4*)&na[grow0 + m * 16];
        const float rn[4] = {rn4.x, rn4.y, rn4.z, rn4.w};
#pragma unroll
        for (int j = 0; j < 4; ++j) {
            const int grow = grow0 + m * 16 + j;
#pragma unroll
            for (int n = 0; n < 4; ++n) {
                const int gcol = gcol0 + n * 16;
                const float d = rn[j] + colnorm[n] - 2.f * acc[m][n][j];
                if (pair == 2) {
#pragma unroll
                    for (int g = 0; g < KG; ++g) lsum[g] += __expf(-d * c_invc[g]);
                } else if (!diagTile) {
#pragma unroll
                    for (int g = 0; g < KG; ++g) lsum[g] += 2.f * __expf(-d * c_invc[g]);
                } else {
                    if (gcol == grow) {
#pragma unroll
                        for (int g = 0; g < KG; ++g) lsum[g] += 1.f;   // exp(0) exactly
                    } else if (gcol > grow) {
#pragma unroll
                        for (int g = 0; g < KG; ++g) lsum[g] += 2.f * __expf(-d * c_invc[g]);
                    }
                }
            }
        }
    }

#pragma unroll
    for (int g = 0; g < KG; ++g) {
        float v = lsum[g];
        for (int off = 32; off > 0; off >>= 1) v += __shfl_down(v, off, 64);
        if (lane == 0) redf[g][w] = v;
    }
    __syncthreads();
    if (tid < KG) {
        const double s = (double)redf[tid][0] + (double)redf[tid][1] +
                         (double)redf[tid][2] + (double)redf[tid][3];
        atomicAdd(&sums[pair * KG + tid], s);
    }
}

// ---------------- h pairs (f32, exact path) ----------------
__global__ void hpairs_kernel(const float* __restrict__ Xs, const float* __restrict__ Xt,
                              const float* __restrict__ ns, const float* __restrict__ nt,
                              float* __restrict__ h) {
    const int gtid = blockIdx.x * blockDim.x + threadIdx.x;
    const int wid = gtid >> 6;
    const int lane = threadIdx.x & 63;
    if (wid >= 1024) return;
    const int i = 2 * wid, j = 2 * wid + 1;
    const float* xsi = Xs + (size_t)i * DIMS;
    const float* xsj = Xs + (size_t)j * DIMS;
    const float* xti = Xt + (size_t)i * DIMS;
    const float* xtj = Xt + (size_t)j * DIMS;
    float dss = 0.f, dtt = 0.f, dst = 0.f, dts = 0.f;
    for (int c = lane; c < DIMS; c += 64) {
        const float a = xsi[c], b = xsj[c], p = xti[c], q = xtj[c];
        dss += a * b; dtt += p * q; dst += a * q; dts += p * b;
    }
    for (int off = 32; off > 0; off >>= 1) {
        dss += __shfl_down(dss, off, 64);
        dtt += __shfl_down(dtt, off, 64);
        dst += __shfl_down(dst, off, 64);
        dts += __shfl_down(dts, off, 64);
    }
    if (lane == 0) {
        const float nsi = ns[i], nsj = ns[j], nti = nt[i], ntj = nt[j];
#pragma unroll
        for (int g = 0; g < KG; ++g) {
            const float ic = c_invc[g];
            const float v = __expf(-(nsi + nsj - 2.f * dss) * ic)
                          + __expf(-(nti + ntj - 2.f * dtt) * ic)
                          - __expf(-(nsi + ntj - 2.f * dst) * ic)
                          - __expf(-(nti + nsj - 2.f * dts) * ic);
            h[g * 1024 + wid] = v;
        }
    }
}

// ---------------- finalize: eta, Q, parallel QP over 31 masks ----------------
__global__ void finalize_kernel(const double* __restrict__ sums,
                                const float* __restrict__ h,
                                float* __restrict__ out) {
    __shared__ float h4[KG][512];
    __shared__ float hsumS[KG];
    __shared__ float qdotS[15];
    __shared__ float red[256];
    const int t = threadIdx.x;

    for (int k = 0; k < KG; ++k)
        for (int j2 = t; j2 < 512; j2 += 256)
            h4[k][j2] = h[k * 1024 + 2 * j2] - h[k * 1024 + 2 * j2 + 1];

    for (int k = 0; k < KG; ++k) {
        float s = 0.f;
        for (int j = t; j < 1024; j += 256) s += h[k * 1024 + j];
        red[t] = s;
        __syncthreads();
        for (int off = 128; off > 0; off >>= 1) {
            if (t < off) red[t] += red[t + off];
            __syncthreads();
        }
        if (t == 0) hsumS[k] = red[0];
        __syncthreads();
    }

    const int wv = t >> 6, ln = t & 63;
    const int pa[15] = {0,0,0,0,0,1,1,1,1,2,2,2,3,3,4};
    const int pb[15] = {0,1,2,3,4,1,2,3,4,2,3,4,3,4,4};
    for (int pi = wv; pi < 15; pi += 4) {
        float s = 0.f;
        for (int j = ln; j < 512; j += 64) s += h4[pa[pi]][j] * h4[pb[pi]][j];
        for (int off = 32; off > 0; off >>= 1) s += __shfl_down(s, off, 64);
        if (ln == 0) qdotS[pi] = s;
    }
    __syncthreads();

    // ---- parallel QP: lane = mask (1..31 valid), wave 0 only ----
    if (t < 64) {
        const double n = 2048.0;
        double Q[KG][KG], p[KG], eta[KG];
        {
            int idx = 0;
            double dd[KG][KG];
#pragma unroll
            for (int a = 0; a < KG; ++a)
#pragma unroll
                for (int b = a; b < KG; ++b) { dd[a][b] = qdotS[idx]; dd[b][a] = qdotS[idx]; ++idx; }
#pragma unroll
            for (int a = 0; a < KG; ++a)
#pragma unroll
                for (int b = 0; b < KG; ++b) {
                    double qp = (4.0 / n) * (dd[a][b] + ((a == b) ? dd[a][a] : 0.0));
                    Q[a][b] = 2.0 * qp + ((a == b) ? 1e-5 : 0.0);
                }
        }
#pragma unroll
        for (int k = 0; k < KG; ++k) {
            p[k] = -2.0 * (double)hsumS[k] / n;
            eta[k] = (sums[k] + sums[KG + k] - 2.0 * sums[2 * KG + k]) / (n * n);
        }

        const int mask = t;
        const bool valid = (mask >= 1 && mask < 32);
        double beta[KG] = {0, 0, 0, 0, 0};
        double obj = INFINITY;

        if (valid) {
            double m[KG];
#pragma unroll
            for (int k = 0; k < KG; ++k) m[k] = (mask >> k) & 1 ? 1.0 : 0.0;
            double M[6][7];
#pragma unroll
            for (int a = 0; a < 6; ++a)
#pragma unroll
                for (int b = 0; b < 7; ++b) M[a][b] = 0.0;
#pragma unroll
            for (int a = 0; a < KG; ++a) {
#pragma unroll
                for (int b = 0; b < KG; ++b) M[a][b] = m[a] * Q[a][b] * m[b];
                M[a][a] += 1.0 - m[a];
                M[a][KG] = m[a];
                M[KG][a] = m[a];
                M[a][6] = -m[a] * p[a];
            }
            M[KG][6] = 1.0;
            // unpivoted GE (diag is 1 / ~1e-5 / Schur != 0 for this family; double is ample)
#pragma unroll
            for (int col = 0; col < 6; ++col) {
                const double dinv = 1.0 / M[col][col];
#pragma unroll
                for (int r = 0; r < 6; ++r) {
                    if (r > col) {
                        const double f = M[r][col] * dinv;
#pragma unroll
                        for (int c = 0; c < 7; ++c)
                            if (c >= col) M[r][c] -= f * M[col][c];
                    }
                }
            }
            double sol[6];
#pragma unroll
            for (int r = 5; r >= 0; --r) {
                double s = M[r][6];
#pragma unroll
                for (int c = 0; c < 6; ++c)
                    if (c > r) s -= M[r][c] * sol[c];
                sol[r] = s / M[r][r];
            }
#pragma unroll
            for (int k = 0; k < KG; ++k) beta[k] = sol[k] * m[k];
            double o = 0.0;
#pragma unroll
            for (int a = 0; a < KG; ++a) {
                double qb = 0.0;
#pragma unroll
                for (int b = 0; b < KG; ++b) qb += Q[a][b] * beta[b];
                o += 0.5 * beta[a] * qb + p[a] * beta[a];
            }
            bool feas = true;
#pragma unroll
            for (int k = 0; k < KG; ++k) if (!(beta[k] >= -1e-7)) feas = false;
            obj = feas ? o : INFINITY;
        }

        // argmin over lanes (first-min tie-break = smallest mask, matching jnp.argmin)
        double bobj = obj;
        int blane = valid ? mask : 9999;
        for (int off = 32; off > 0; off >>= 1) {
            const double o2 = __shfl_down(bobj, off, 64);
            const int l2 = __shfl_down(blane, off, 64);
            if (o2 < bobj || (o2 == bobj && l2 < blane)) { bobj = o2; blane = l2; }
        }
        bobj = __shfl(bobj, 0, 64);
        blane = __shfl(blane, 0, 64);
        if (bobj > 1e300) blane = 1;   // all infeasible -> argmin over infs = mask 1

        if (mask == blane) {
            double o = 0.0;
#pragma unroll
            for (int k = 0; k < KG; ++k) o += eta[k] * beta[k];
            out[0] = (float)o;
        }
    }
}

// ---------------- launch ----------------
extern "C" void kernel_launch(void* const* d_in, const int* in_sizes, int n_in,
                              void* d_out, int out_size, void* d_ws, size_t ws_size,
                              hipStream_t stream) {
    const float* Xs = (const float*)d_in[0];
    const float* Xt = (const float*)d_in[1];
    float* out = (float*)d_out;

    char* ws = (char*)d_ws;
    double* sums = (double*)ws;                    // 15 doubles, reserve 128 B
    float* ns = (float*)(ws + 128);                // 2048 f32
    float* nt = (float*)(ws + 128 + 8192);         // 2048 f32
    float* h  = (float*)(ws + 128 + 16384);        // 5*1024 f32

    hipMemsetAsync(d_ws, 0, 128, stream);
    rownorm_kernel<<<dim3(NROWS, 2), 256, 0, stream>>>(Xs, Xt, ns, nt);
    gram_mfma_kernel<<<dim3(16, 16, 3), 256, 0, stream>>>(Xs, Xt, ns, nt, sums);
    hpairs_kernel<<<dim3(256), dim3(256), 0, stream>>>(Xs, Xt, ns, nt, h);
    finalize_kernel<<<1, 256, 0, stream>>>(sums, h, out);
}

// Round 3
// 58.940 us; speedup vs baseline: 5.5986x; 1.1099x over previous
//
#include <hip/hip_runtime.h>
#include <math.h>

#define NROWS 2048
#define DIMS  512
#define KG    5
#define BM    128
#define BKF   64

// invc[k] = 1/(2*gamma^2), gammas = {2,1,0.5,0.25,0.125}
__device__ __constant__ float c_invc[KG] = {0.125f, 0.5f, 2.0f, 8.0f, 32.0f};

typedef __attribute__((ext_vector_type(8))) short bf16x8;
typedef __attribute__((ext_vector_type(4))) float f32x4;

__device__ __forceinline__ unsigned short f2bf(float x) {
    unsigned int u = __float_as_uint(x);
    unsigned int r = (u + 0x7fffu + ((u >> 16) & 1u)) >> 16;
    return (unsigned short)r;
}

__device__ __forceinline__ void gload_lds16(const void* g, void* l) {
    __builtin_amdgcn_global_load_lds(
        (const __attribute__((address_space(1))) unsigned int*)g,
        (__attribute__((address_space(3))) unsigned int*)l, 16, 0, 0);
}

// ---------------- fused convert (f32->bf16) + row norms + zero sums ----------------
// 1024 blocks x 256 threads; 4 rows/block (1 wave per row), 4096 virtual rows (Xs|Xt)
__global__ void convert_norm_kernel(const float* __restrict__ Xs, const float* __restrict__ Xt,
                                    unsigned short* __restrict__ Xsb, unsigned short* __restrict__ Xtb,
                                    float* __restrict__ ns, float* __restrict__ nt,
                                    double* __restrict__ sums) {
    if (blockIdx.x == 0 && threadIdx.x < 16) sums[threadIdx.x] = 0.0;

    const int vrow = blockIdx.x * 4 + (threadIdx.x >> 6);
    const int lane = threadIdx.x & 63;
    const bool isT = vrow >= NROWS;
    const int r = isT ? vrow - NROWS : vrow;
    const float* X = isT ? Xt : Xs;
    unsigned short* Xb = isT ? Xtb : Xsb;
    float* nrm = isT ? nt : ns;

    const float* src = X + (size_t)r * DIMS + lane * 8;
    const float4 v0 = *(const float4*)src;
    const float4 v1 = *(const float4*)(src + 4);

    float s = v0.x * v0.x + v0.y * v0.y + v0.z * v0.z + v0.w * v0.w
            + v1.x * v1.x + v1.y * v1.y + v1.z * v1.z + v1.w * v1.w;

    bf16x8 o;
    o[0] = (short)f2bf(v0.x); o[1] = (short)f2bf(v0.y);
    o[2] = (short)f2bf(v0.z); o[3] = (short)f2bf(v0.w);
    o[4] = (short)f2bf(v1.x); o[5] = (short)f2bf(v1.y);
    o[6] = (short)f2bf(v1.z); o[7] = (short)f2bf(v1.w);
    *(bf16x8*)(Xb + (size_t)r * DIMS + lane * 8) = o;

    for (int off = 32; off > 0; off >>= 1) s += __shfl_down(s, off, 64);
    if (lane == 0) nrm[r] = s;
}

// ---------------- MFMA gram on bf16 + exp + reduce ----------------
// pair z: 0 = XX (upper tri, x2, diag analytic), 1 = YY (same), 2 = XY (full)
// LDS layout: row r occupies 128 B (8 chunks of 16 B); chunk c stored at slot c^(r&7).
// Staging uses global_load_lds with pre-swizzled SOURCE; reads apply the same XOR.
__global__ __launch_bounds__(256) void gram_bf16_kernel(const unsigned short* __restrict__ Xsb,
                                                        const unsigned short* __restrict__ Xtb,
                                                        const float* __restrict__ ns,
                                                        const float* __restrict__ nt,
                                                        double* __restrict__ sums) {
    const int pair = blockIdx.z;
    const int bx = blockIdx.x, by = blockIdx.y;
    if (pair < 2 && bx < by) return;   // triangular grid for symmetric pairs

    const unsigned short* A = (pair == 1) ? Xtb : Xsb;
    const unsigned short* B = (pair == 0) ? Xsb : Xtb;
    const float* na = (pair == 1) ? nt : ns;
    const float* nb = (pair == 0) ? ns : nt;
    const int row0 = by * BM, col0 = bx * BM;

    __shared__ unsigned short Asm[BM * BKF];   // 16 KB
    __shared__ unsigned short Bsm[BM * BKF];   // 16 KB
    __shared__ float redf[KG][4];

    const int tid = threadIdx.x;
    const int lane = tid & 63;
    const int w = tid >> 6;
    const int wr = w >> 1, wc = w & 1;         // 2x2 wave grid, 64x64 per wave

    f32x4 acc[4][4] = {};

    const int lrow8  = lane >> 3;              // row within 8-row stripe
    const int lchunk = (lane & 7) ^ lrow8;     // pre-swizzled source chunk

    for (int kt = 0; kt < DIMS; kt += BKF) {
#pragma unroll
        for (int q = 0; q < 4; ++q) {
            const int r0 = w * 32 + q * 8;     // wave-uniform LDS base row
            const int row = r0 + lrow8;
            gload_lds16(A + (size_t)(row0 + row) * DIMS + kt + lchunk * 8, Asm + r0 * 64);
            gload_lds16(B + (size_t)(col0 + row) * DIMS + kt + lchunk * 8, Bsm + r0 * 64);
        }
        __syncthreads();

        const int h16 = lane >> 4;
        bf16x8 af[2][4], bv[2][4];
#pragma unroll
        for (int kk = 0; kk < 2; ++kk)
#pragma unroll
            for (int m = 0; m < 4; ++m) {
                const int ra = wr * 64 + m * 16 + (lane & 15);
                af[kk][m] = *(const bf16x8*)((const char*)Asm + ra * 128 + (((kk * 4 + h16) ^ (ra & 7)) * 16));
                const int rb = wc * 64 + m * 16 + (lane & 15);
                bv[kk][m] = *(const bf16x8*)((const char*)Bsm + rb * 128 + (((kk * 4 + h16) ^ (rb & 7)) * 16));
            }
#pragma unroll
        for (int m = 0; m < 4; ++m)
#pragma unroll
            for (int n = 0; n < 4; ++n) {
                acc[m][n] = __builtin_amdgcn_mfma_f32_16x16x32_bf16(af[0][m], bv[0][n], acc[m][n], 0, 0, 0);
                acc[m][n] = __builtin_amdgcn_mfma_f32_16x16x32_bf16(af[1][m], bv[1][n], acc[m][n], 0, 0, 0);
            }
        __syncthreads();
    }

    // epilogue: C/D layout col = lane&15, row = (lane>>4)*4 + reg
    float lsum[KG] = {0.f, 0.f, 0.f, 0.f, 0.f};
    const int gcol0 = col0 + wc * 64 + (lane & 15);
    const int grow0 = row0 + wr * 64 + (lane >> 4) * 4;
    const bool diagTile = (pair < 2) && (bx == by);

    float colnorm[4];
#pragma unroll
    for (int n = 0; n < 4; ++n) colnorm[n] = nb[gcol0 + n * 16];

#pragma unroll
    for (int m = 0; m < 4; ++m) {
        const float4 rn4 = *(const float4*)&na[grow0 + m * 16];
        const float rn[4] = {rn4.x, rn4.y, rn4.z, rn4.w};
#pragma unroll
        for (int j = 0; j < 4; ++j) {
            const int grow = grow0 + m * 16 + j;
#pragma unroll
            for (int n = 0; n < 4; ++n) {
                const int gcol = gcol0 + n * 16;
                const float d = rn[j] + colnorm[n] - 2.f * acc[m][n][j];
                if (pair == 2) {
#pragma unroll
                    for (int g = 0; g < KG; ++g) lsum[g] += __expf(-d * c_invc[g]);
                } else if (!diagTile) {
#pragma unroll
                    for (int g = 0; g < KG; ++g) lsum[g] += 2.f * __expf(-d * c_invc[g]);
                } else {
                    if (gcol == grow) {
#pragma unroll
                        for (int g = 0; g < KG; ++g) lsum[g] += 1.f;   // exp(0) exactly
                    } else if (gcol > grow) {
#pragma unroll
                        for (int g = 0; g < KG; ++g) lsum[g] += 2.f * __expf(-d * c_invc[g]);
                    }
                }
            }
        }
    }

#pragma unroll
    for (int g = 0; g < KG; ++g) {
        float v = lsum[g];
        for (int off = 32; off > 0; off >>= 1) v += __shfl_down(v, off, 64);
        if (lane == 0) redf[g][w] = v;
    }
    __syncthreads();
    if (tid < KG) {
        const double s = (double)redf[tid][0] + (double)redf[tid][1] +
                         (double)redf[tid][2] + (double)redf[tid][3];
        atomicAdd(&sums[pair * KG + tid], s);
    }
}

// ---------------- h pairs (f32, exact path) ----------------
__global__ void hpairs_kernel(const float* __restrict__ Xs, const float* __restrict__ Xt,
                              const float* __restrict__ ns, const float* __restrict__ nt,
                              float* __restrict__ h) {
    const int gtid = blockIdx.x * blockDim.x + threadIdx.x;
    const int wid = gtid >> 6;
    const int lane = threadIdx.x & 63;
    if (wid >= 1024) return;
    const int i = 2 * wid, j = 2 * wid + 1;
    const float* xsi = Xs + (size_t)i * DIMS;
    const float* xsj = Xs + (size_t)j * DIMS;
    const float* xti = Xt + (size_t)i * DIMS;
    const float* xtj = Xt + (size_t)j * DIMS;
    float dss = 0.f, dtt = 0.f, dst = 0.f, dts = 0.f;
    for (int c = lane; c < DIMS; c += 64) {
        const float a = xsi[c], b = xsj[c], p = xti[c], q = xtj[c];
        dss += a * b; dtt += p * q; dst += a * q; dts += p * b;
    }
    for (int off = 32; off > 0; off >>= 1) {
        dss += __shfl_down(dss, off, 64);
        dtt += __shfl_down(dtt, off, 64);
        dst += __shfl_down(dst, off, 64);
        dts += __shfl_down(dts, off, 64);
    }
    if (lane == 0) {
        const float nsi = ns[i], nsj = ns[j], nti = nt[i], ntj = nt[j];
#pragma unroll
        for (int g = 0; g < KG; ++g) {
            const float ic = c_invc[g];
            const float v = __expf(-(nsi + nsj - 2.f * dss) * ic)
                          + __expf(-(nti + ntj - 2.f * dtt) * ic)
                          - __expf(-(nsi + ntj - 2.f * dst) * ic)
                          - __expf(-(nti + nsj - 2.f * dts) * ic);
            h[g * 1024 + wid] = v;
        }
    }
}

// ---------------- finalize: eta, Q, parallel QP over 31 masks ----------------
__global__ void finalize_kernel(const double* __restrict__ sums,
                                const float* __restrict__ h,
                                float* __restrict__ out) {
    __shared__ float h4[KG][512];
    __shared__ float hsumS[KG];
    __shared__ float qdotS[15];
    __shared__ float redh[KG][4];
    const int t = threadIdx.x;
    const int wv = t >> 6, ln = t & 63;

    for (int k = 0; k < KG; ++k)
        for (int j2 = t; j2 < 512; j2 += 256)
            h4[k][j2] = h[k * 1024 + 2 * j2] - h[k * 1024 + 2 * j2 + 1];

    // single-pass h sums: 5 accumulators per thread, wave shuffle, one barrier
    {
        float s[KG] = {0.f, 0.f, 0.f, 0.f, 0.f};
        for (int j = t; j < 1024; j += 256)
#pragma unroll
            for (int k = 0; k < KG; ++k) s[k] += h[k * 1024 + j];
#pragma unroll
        for (int k = 0; k < KG; ++k) {
            float v = s[k];
            for (int off = 32; off > 0; off >>= 1) v += __shfl_down(v, off, 64);
            if (ln == 0) redh[k][wv] = v;
        }
    }
    __syncthreads();
    if (t < KG) hsumS[t] = redh[t][0] + redh[t][1] + redh[t][2] + redh[t][3];
    __syncthreads();

    const int pa[15] = {0,0,0,0,0,1,1,1,1,2,2,2,3,3,4};
    const int pb[15] = {0,1,2,3,4,1,2,3,4,2,3,4,3,4,4};
    for (int pi = wv; pi < 15; pi += 4) {
        float s = 0.f;
        for (int j = ln; j < 512; j += 64) s += h4[pa[pi]][j] * h4[pb[pi]][j];
        for (int off = 32; off > 0; off >>= 1) s += __shfl_down(s, off, 64);
        if (ln == 0) qdotS[pi] = s;
    }
    __syncthreads();

    // ---- parallel QP: lane = mask (1..31 valid), wave 0 only ----
    if (t < 64) {
        const double n = 2048.0;
        double Q[KG][KG], p[KG], eta[KG];
        {
            int idx = 0;
            double dd[KG][KG];
#pragma unroll
            for (int a = 0; a < KG; ++a)
#pragma unroll
                for (int b = a; b < KG; ++b) { dd[a][b] = qdotS[idx]; dd[b][a] = qdotS[idx]; ++idx; }
#pragma unroll
            for (int a = 0; a < KG; ++a)
#pragma unroll
                for (int b = 0; b < KG; ++b) {
                    double qp = (4.0 / n) * (dd[a][b] + ((a == b) ? dd[a][a] : 0.0));
                    Q[a][b] = 2.0 * qp + ((a == b) ? 1e-5 : 0.0);
                }
        }
#pragma unroll
        for (int k = 0; k < KG; ++k) {
            p[k] = -2.0 * (double)hsumS[k] / n;
            eta[k] = (sums[k] + sums[KG + k] - 2.0 * sums[2 * KG + k]) / (n * n);
        }

        const int mask = t;
        const bool valid = (mask >= 1 && mask < 32);
        double beta[KG] = {0, 0, 0, 0, 0};
        double obj = INFINITY;

        if (valid) {
            double m[KG];
#pragma unroll
            for (int k = 0; k < KG; ++k) m[k] = (mask >> k) & 1 ? 1.0 : 0.0;
            double M[6][7];
#pragma unroll
            for (int a = 0; a < 6; ++a)
#pragma unroll
                for (int b = 0; b < 7; ++b) M[a][b] = 0.0;
#pragma unroll
            for (int a = 0; a < KG; ++a) {
#pragma unroll
                for (int b = 0; b < KG; ++b) M[a][b] = m[a] * Q[a][b] * m[b];
                M[a][a] += 1.0 - m[a];
                M[a][KG] = m[a];
                M[KG][a] = m[a];
                M[a][6] = -m[a] * p[a];
            }
            M[KG][6] = 1.0;
#pragma unroll
            for (int col = 0; col < 6; ++col) {
                const double dinv = 1.0 / M[col][col];
#pragma unroll
                for (int r = 0; r < 6; ++r) {
                    if (r > col) {
                        const double f = M[r][col] * dinv;
#pragma unroll
                        for (int c = 0; c < 7; ++c)
                            if (c >= col) M[r][c] -= f * M[col][c];
                    }
                }
            }
            double sol[6];
#pragma unroll
            for (int r = 5; r >= 0; --r) {
                double s = M[r][6];
#pragma unroll
                for (int c = 0; c < 6; ++c)
                    if (c > r) s -= M[r][c] * sol[c];
                sol[r] = s / M[r][r];
            }
#pragma unroll
            for (int k = 0; k < KG; ++k) beta[k] = sol[k] * m[k];
            double o = 0.0;
#pragma unroll
            for (int a = 0; a < KG; ++a) {
                double qb = 0.0;
#pragma unroll
                for (int b = 0; b < KG; ++b) qb += Q[a][b] * beta[b];
                o += 0.5 * beta[a] * qb + p[a] * beta[a];
            }
            bool feas = true;
#pragma unroll
            for (int k = 0; k < KG; ++k) if (!(beta[k] >= -1e-7)) feas = false;
            obj = feas ? o : INFINITY;
        }

        double bobj = obj;
        int blane = valid ? mask : 9999;
        for (int off = 32; off > 0; off >>= 1) {
            const double o2 = __shfl_down(bobj, off, 64);
            const int l2 = __shfl_down(blane, off, 64);
            if (o2 < bobj || (o2 == bobj && l2 < blane)) { bobj = o2; blane = l2; }
        }
        bobj = __shfl(bobj, 0, 64);
        blane = __shfl(blane, 0, 64);
        if (bobj > 1e300) blane = 1;

        if (mask == blane) {
            double o = 0.0;
#pragma unroll
            for (int k = 0; k < KG; ++k) o += eta[k] * beta[k];
            out[0] = (float)o;
        }
    }
}

// ---------------- launch ----------------
extern "C" void kernel_launch(void* const* d_in, const int* in_sizes, int n_in,
                              void* d_out, int out_size, void* d_ws, size_t ws_size,
                              hipStream_t stream) {
    const float* Xs = (const float*)d_in[0];
    const float* Xt = (const float*)d_in[1];
    float* out = (float*)d_out;

    char* ws = (char*)d_ws;
    double* sums = (double*)ws;                          // 16 doubles, 128 B
    float* ns = (float*)(ws + 128);                      // 2048 f32
    float* nt = (float*)(ws + 128 + 8192);               // 2048 f32
    float* h  = (float*)(ws + 128 + 16384);              // 5*1024 f32
    unsigned short* Xsb = (unsigned short*)(ws + 40960);           // 2 MB bf16
    unsigned short* Xtb = (unsigned short*)(ws + 40960 + 2097152); // 2 MB bf16
    // total ws use ~4.25 MB (ws_size ~256 MB per harness poison-fill WRITE_SIZE)

    convert_norm_kernel<<<1024, 256, 0, stream>>>(Xs, Xt, Xsb, Xtb, ns, nt, sums);
    gram_bf16_kernel<<<dim3(16, 16, 3), 256, 0, stream>>>(Xsb, Xtb, ns, nt, sums);
    hpairs_kernel<<<256, 256, 0, stream>>>(Xs, Xt, ns, nt, h);
    finalize_kernel<<<1, 256, 0, stream>>>(sums, h, out);
}